// Round 11
// baseline (211.128 us; speedup 1.0000x reference)
//
#include <hip/hip_runtime.h>
#include <hip/hip_bf16.h>

#define D 64

typedef float f32x4 __attribute__((ext_vector_type(4)));

// ---- kernel 0: zero counts (int4, includes padding) ----
__global__ void zero_kernel(int4* __restrict__ p, int n4) {
    int i = blockIdx.x * blockDim.x + threadIdx.x;
    if (i < n4) p[i] = make_int4(0, 0, 0, 0);
}

// ---- kernel 1: histogram counts[dst[e]]++ (int4 reads) ----
__global__ void count_kernel(const int4* __restrict__ dst4, int* __restrict__ counts, int E4) {
    int i = blockIdx.x * blockDim.x + threadIdx.x;
    if (i < E4) {
        int4 d = dst4[i];
        atomicAdd(&counts[d.x], 1);
        atomicAdd(&counts[d.y], 1);
        atomicAdd(&counts[d.z], 1);
        atomicAdd(&counts[d.w], 1);
    }
}

// ---- kernel 2: single-block exclusive scan (int4, shfl, 2 barriers/chunk) + Wc/bc combine ----
__global__ void scan4_kernel(const int4* __restrict__ counts4, int N4, int N,
                             int4* __restrict__ offsets4, int4* __restrict__ cursor4,
                             int* __restrict__ offsets,
                             const float* __restrict__ Wp, const float* __restrict__ Wu,
                             const float* __restrict__ bp,
                             float* __restrict__ Wc, float* __restrict__ bc) {
    __shared__ int wsum[16];
    __shared__ float wu[D * D];
    __shared__ float wp[D * D];
    int t = threadIdx.x;
    for (int i = t; i < D * D; i += 1024) { wu[i] = Wu[i]; wp[i] = Wp[i]; }

    int wave = t >> 6, lane = t & 63;
    int carry = 0;
    int nchunk = (N4 + 1023) / 1024;
    for (int ch = 0; ch < nchunk; ++ch) {
        int i = ch * 1024 + t;
        int4 v = make_int4(0, 0, 0, 0);
        if (i < N4) v = counts4[i];
        int vs = v.x + v.y + v.z + v.w;
        int s = vs;
        #pragma unroll
        for (int off = 1; off < 64; off <<= 1) {
            int x = __shfl_up(s, off);
            if (lane >= off) s += x;
        }
        if (lane == 63) wsum[wave] = s;
        __syncthreads();
        int wbase = 0, total = 0;
        #pragma unroll
        for (int w = 0; w < 16; ++w) {
            int x = wsum[w];
            total += x;
            if (w < wave) wbase += x;
        }
        if (i < N4) {
            int e0 = s - vs + wbase + carry;
            int4 o;
            o.x = e0;
            o.y = e0 + v.x;
            o.z = o.y + v.y;
            o.w = o.z + v.z;
            offsets4[i] = o;
            cursor4[i] = o;
        }
        carry += total;
        __syncthreads();
    }
    if (t == 0) offsets[N] = carry;   // == E

    __syncthreads();
    for (int idx = t; idx < D * D; idx += 1024) {
        int d = idx >> 6, j = idx & 63;
        float acc = 0.f;
        #pragma unroll
        for (int k = 0; k < D; ++k) acc = fmaf(wp[d * D + k], wu[k * D + j], acc);
        Wc[idx] = acc;
    }
    if (t < D) {
        float acc = 0.f;
        #pragma unroll
        for (int k = 0; k < D; ++k) acc = fmaf(bp[k], wu[k * D + t], acc);
        bc[t] = acc;
    }
}

// ---- kernel 3: scatter edge ids into CSR slots (int4 reads) ----
__global__ void fill_kernel(const int4* __restrict__ dst4, int* __restrict__ cursor,
                            int* __restrict__ csr, int E4) {
    int i = blockIdx.x * blockDim.x + threadIdx.x;
    if (i < E4) {
        int4 d = dst4[i];
        int e = i * 4;
        csr[atomicAdd(&cursor[d.x], 1)] = e + 0;
        csr[atomicAdd(&cursor[d.y], 1)] = e + 1;
        csr[atomicAdd(&cursor[d.z], 1)] = e + 2;
        csr[atomicAdd(&cursor[d.w], 1)] = e + 3;
    }
}

// ---- kernel 3.5: L3 warm — stream edge_attrs with allocating loads, sink results ----
__global__ __launch_bounds__(256) void warm_kernel(const f32x4* __restrict__ a, int n16) {
    float s = 0.f;
    int stride = gridDim.x * 256;
    for (int i = blockIdx.x * 256 + threadIdx.x; i < n16; i += stride) {
        f32x4 v = a[i];               // normal load: allocates in L2/L3
        s += v.x + v.y + v.z + v.w;
    }
    asm volatile("" :: "v"(s));       // keep loads live, no store
}

// ---- kernel 4: per-node gather (float4, 8 edges in flight) + mean + fused matmul ----
__global__ __launch_bounds__(256) void node_kernel(
        const float4* __restrict__ attrs4, const int* __restrict__ csr,
        const int* __restrict__ offsets,
        const float* __restrict__ Wc, const float* __restrict__ bc,
        const float* __restrict__ ub, float* __restrict__ out, int N) {
    __shared__ float wlds[D * D];
    __shared__ float blds[D];
    __shared__ float ulds[D];
    __shared__ int soff[5];
    int t = threadIdx.x;
    int nbase = blockIdx.x * 4;
    if (t < 5) {
        int nn = nbase + t;
        soff[t] = offsets[(nn <= N) ? nn : N];
    }
    #pragma unroll
    for (int i = t; i < D * D; i += 256) wlds[i] = Wc[i];
    if (t < D) { blds[t] = bc[t]; ulds[t] = ub[t]; }
    __syncthreads();

    int wave = t >> 6, lane = t & 63;
    int n = nbase + wave;
    if (n >= N) return;

    int off = soff[wave];
    int cnt = soff[wave + 1] - off;

    int g = lane >> 4;
    int q = lane & 15;

    float4 acc0 = make_float4(0.f, 0.f, 0.f, 0.f);
    float4 acc1 = make_float4(0.f, 0.f, 0.f, 0.f);
    for (int base = 0; base < cnt; base += 64) {
        int m = cnt - base; if (m > 64) m = 64;
        int idxv = (lane < m) ? csr[off + base + lane] : 0;
        int jj = 0;
        for (; jj + 8 <= m; jj += 8) {
            int e0 = __shfl(idxv, jj + g);
            int e1 = __shfl(idxv, jj + 4 + g);
            float4 a0 = attrs4[(size_t)e0 * 16 + q];
            float4 a1 = attrs4[(size_t)e1 * 16 + q];
            acc0.x += a0.x; acc0.y += a0.y; acc0.z += a0.z; acc0.w += a0.w;
            acc1.x += a1.x; acc1.y += a1.y; acc1.z += a1.z; acc1.w += a1.w;
        }
        for (; jj < m; jj += 4) {
            int sel = jj + g;
            int e = __shfl(idxv, sel);
            if (sel < m) {
                float4 a = attrs4[(size_t)e * 16 + q];
                acc0.x += a.x; acc0.y += a.y; acc0.z += a.z; acc0.w += a.w;
            }
        }
    }
    float4 acc = make_float4(acc0.x + acc1.x, acc0.y + acc1.y,
                             acc0.z + acc1.z, acc0.w + acc1.w);
    acc.x += __shfl_xor(acc.x, 16); acc.y += __shfl_xor(acc.y, 16);
    acc.z += __shfl_xor(acc.z, 16); acc.w += __shfl_xor(acc.w, 16);
    acc.x += __shfl_xor(acc.x, 32); acc.y += __shfl_xor(acc.y, 32);
    acc.z += __shfl_xor(acc.z, 32); acc.w += __shfl_xor(acc.w, 32);

    float inv = (cnt > 0) ? 1.f / (float)cnt : 0.f;
    float marr[4] = { acc.x * inv, acc.y * inv, acc.z * inv, acc.w * inv };

    float accO = ulds[lane] + ((cnt > 0) ? blds[lane] : 0.f);
    #pragma unroll
    for (int d = 0; d < D; ++d) {
        float mv = __shfl(marr[d & 3], d >> 2);
        accO = fmaf(mv, wlds[d * D + lane], accO);
    }
    out[(size_t)n * D + lane] = accO;
}

extern "C" void kernel_launch(void* const* d_in, const int* in_sizes, int n_in,
                              void* d_out, int out_size, void* d_ws, size_t ws_size,
                              hipStream_t stream) {
    const float* edge_attrs = (const float*)d_in[0];
    const float* proj_W     = (const float*)d_in[1];
    const float* proj_b     = (const float*)d_in[2];
    const float* upd_W      = (const float*)d_in[3];
    const float* upd_b      = (const float*)d_in[4];
    const int*   dst        = (const int*)d_in[5];

    const int E = in_sizes[0] / D;
    const int N = out_size / D;
    const int E4 = E / 4;
    const int N4 = (N + 3) / 4;
    const int Npad = N4 * 4 + 4;

    int*   counts  = (int*)d_ws;
    int*   offsets = counts + Npad;
    int*   cursor  = offsets + Npad;
    int*   csr     = cursor + Npad;
    float* Wc      = (float*)(csr + E);
    float* bc      = Wc + D * D;

    zero_kernel<<<(N4 + 255) / 256, 256, 0, stream>>>((int4*)counts, N4);
    count_kernel<<<(E4 + 255) / 256, 256, 0, stream>>>((const int4*)dst, counts, E4);
    scan4_kernel<<<1, 1024, 0, stream>>>((const int4*)counts, N4, N,
                                         (int4*)offsets, (int4*)cursor, offsets,
                                         proj_W, upd_W, proj_b, Wc, bc);
    fill_kernel<<<(E4 + 255) / 256, 256, 0, stream>>>((const int4*)dst, cursor, csr, E4);
    warm_kernel<<<2048, 256, 0, stream>>>((const f32x4*)edge_attrs, E * 16);

    int blocks_n = (N + 3) / 4;
    node_kernel<<<blocks_n, 256, 0, stream>>>((const float4*)edge_attrs, csr, offsets,
                                              Wc, bc, upd_b, (float*)d_out, N);
}